// Round 4
// baseline (541.167 us; speedup 1.0000x reference)
//
#include <hip/hip_runtime.h>
#include <hip/hip_bf16.h>

// MoE expert collection: out = silu(x @ W_e + b_e), 16 experts, equal token split.
// x: [65536][1024] f32, W: [1024][2048][16] f32, b: [2048][16] f32, out: [65536][2048] f32.
//
// R4: 256x256x64 4-phase merged schedule (32-MFMA clusters; halves barrier count vs R3's
// 8-phase), counted vmcnt(4), T2 pre-swizzled operands, T5 setprio. Fused prep kernel.
// Fallbacks: R2 kernel (if 128KB LDS attr fails), R1 kernel (if ws < 192 MiB).

#define E_ 16
#define DIN 1024
#define DOUT 2048
#define NTOK 65536
#define NPE (NTOK / E_)
#define NKT (DIN / 64)    // 16 K-tiles of 64
#define NI (NKT / 2)      // 8 iterations, 2 K-tiles each

typedef __attribute__((ext_vector_type(8))) short short8;
typedef __attribute__((ext_vector_type(4))) float f32x4;

__device__ __forceinline__ unsigned short f2bf(float f) {
  union { float f; unsigned int u; } v; v.f = f;
  unsigned int u = v.u;
  return (unsigned short)((u + 0x7fffu + ((u >> 16) & 1u)) >> 16);  // RNE
}

__device__ __forceinline__ void gload_lds16(const void* g, void* l) {
  __builtin_amdgcn_global_load_lds(
      (const __attribute__((address_space(1))) void*)g,
      (__attribute__((address_space(3))) void*)l, 16, 0, 0);
}

// ---------------- fused prep: blocks [0,2048) do W, [2048,4096) do x ----------------
// prep_w: W [k][o][e] f32 -> Wt [e][o][k] bf16, 16B-blocks XOR-swizzled by (o&7).
// prep_x: x [m][k] f32 -> xs [m][k] bf16, 16B-blocks XOR-swizzled by (m&7).
__global__ __launch_bounds__(256)
void prep_fused(const float* __restrict__ x, unsigned short* __restrict__ xs,
                const float* __restrict__ W, unsigned short* __restrict__ Wt) {
  __shared__ unsigned short tile[16][32][33];
  const int tid = threadIdx.x;
  if (blockIdx.x < 2048) {
    const int bid = blockIdx.x;
    const int k0 = (bid >> 6) * 32;
    const int o0 = (bid & 63) * 32;
    for (int p = tid; p < 1024; p += 256) {
      const int k = p >> 5, o = p & 31;
      const float4* src = (const float4*)(W + ((size_t)(k0 + k) * DOUT + (o0 + o)) * 16);
      float4 v0 = src[0], v1 = src[1], v2 = src[2], v3 = src[3];
      const float vv[16] = {v0.x, v0.y, v0.z, v0.w, v1.x, v1.y, v1.z, v1.w,
                            v2.x, v2.y, v2.z, v2.w, v3.x, v3.y, v3.z, v3.w};
      #pragma unroll
      for (int e = 0; e < 16; ++e) tile[e][k][o] = f2bf(vv[e]);
    }
    __syncthreads();
    for (int c = tid; c < 2048; c += 256) {
      const int kc = c & 3, o = (c >> 2) & 31, e = c >> 7;
      unsigned short vals[8];
      #pragma unroll
      for (int j = 0; j < 8; ++j) vals[j] = tile[e][kc * 8 + j][o];
      uint4 wv;
      wv.x = vals[0] | ((unsigned)vals[1] << 16);
      wv.y = vals[2] | ((unsigned)vals[3] << 16);
      wv.z = vals[4] | ((unsigned)vals[5] << 16);
      wv.w = vals[6] | ((unsigned)vals[7] << 16);
      const int jb = (k0 >> 3) + kc;
      const int jbs = (jb & ~7) | ((jb & 7) ^ (o & 7));
      *(uint4*)(Wt + (size_t)e * (DOUT * DIN) + (size_t)(o0 + o) * DIN + jbs * 8) = wv;
    }
  } else {
    const int nunits = NTOK * (DIN / 8);
    for (int u = (blockIdx.x - 2048) * 256 + tid; u < nunits; u += 2048 * 256) {
      const int m = u >> 7;
      const int j = u & 127;
      const float4* src = (const float4*)(x + (size_t)m * DIN + j * 8);
      const float4 a = src[0], b = src[1];
      uint4 v;
      v.x = f2bf(a.x) | ((unsigned)f2bf(a.y) << 16);
      v.y = f2bf(a.z) | ((unsigned)f2bf(a.w) << 16);
      v.z = f2bf(b.x) | ((unsigned)f2bf(b.y) << 16);
      v.w = f2bf(b.z) | ((unsigned)f2bf(b.w) << 16);
      const int js = (j & ~7) | ((j & 7) ^ (m & 7));
      *(uint4*)(xs + (size_t)m * DIN + js * 8) = v;
    }
  }
}

// ---------------- R4 main: 256^2 4-phase merged GEMM ----------------
__global__ __launch_bounds__(512, 2)
void moe_gemm4p(const unsigned short* __restrict__ xs, const unsigned short* __restrict__ Wt,
                const float* __restrict__ bias, float* __restrict__ out) {
  extern __shared__ char smem[];   // 128 KiB: A slots [0,64K), B slots [64K,128K)

  const int bid = blockIdx.x;
  const int swz = (bid & 7) * 256 + (bid >> 3);   // bijective: 2048 % 8 == 0
  const int e  = swz >> 7;
  const int mb = (swz >> 3) & 15;
  const int nb = swz & 7;
  const int row0 = e * NPE + mb * 256;
  const int col0 = nb * 256;

  const int tid = threadIdx.x;
  const int lane = tid & 63;
  const int w = tid >> 6;
  const int wm = w >> 2, wn = w & 3;   // 2M x 4N wave grid, 128x64 out per wave
  const int l15 = lane & 15;

  const char* xa  = (const char*)xs + (size_t)row0 * (DIN * 2);
  const char* wbg = (const char*)(Wt + (size_t)e * (DOUT * DIN) + (size_t)col0 * DIN);

  const int crow0 = w * 16 + (lane >> 3);
  const int kb16  = (lane & 7) * 16;
  const int dch0  = w * 2048;

  const int hi16  = (lane >> 4) << 4;
  const int sw7   = (lane & 7) << 4;
  const int koff0 = (0  | hi16) ^ sw7;
  const int koff1 = (64 | hi16) ^ sw7;

  f32x4 acc[8][4];
  #pragma unroll
  for (int i = 0; i < 8; ++i)
    #pragma unroll
    for (int j = 0; j < 4; ++j) acc[i][j] = (f32x4){0.f, 0.f, 0.f, 0.f};

  short8 a[8], b[8];

#define STAGE_A(slot, half, kt) do { \
    gload_lds16(xa + (size_t)((half) * 128 + crow0) * (DIN * 2) + (kt) * 128 + kb16, \
                smem + (slot) * 32768 + (half) * 16384 + dch0); \
    gload_lds16(xa + (size_t)((half) * 128 + crow0 + 8) * (DIN * 2) + (kt) * 128 + kb16, \
                smem + (slot) * 32768 + (half) * 16384 + dch0 + 1024); \
  } while (0)

#define STAGE_B(slot, half, kt) do { \
    gload_lds16(wbg + (size_t)((half) * 128 + crow0) * (DIN * 2) + (kt) * 128 + kb16, \
                smem + 65536 + (slot) * 32768 + (half) * 16384 + dch0); \
    gload_lds16(wbg + (size_t)((half) * 128 + crow0 + 8) * (DIN * 2) + (kt) * 128 + kb16, \
                smem + 65536 + (slot) * 32768 + (half) * 16384 + dch0 + 1024); \
  } while (0)

#define READ_A(slot, qm_) do { \
    _Pragma("unroll") \
    for (int mf = 0; mf < 4; ++mf) { \
      const int r_ = wm * 128 + (qm_) * 64 + mf * 16 + l15; \
      const char* p_ = smem + (slot) * 32768 + r_ * 128; \
      a[mf * 2 + 0] = *(const short8*)(p_ + koff0); \
      a[mf * 2 + 1] = *(const short8*)(p_ + koff1); \
    } \
  } while (0)

#define READ_B_ALL(slot) do { \
    _Pragma("unroll") \
    for (int nf = 0; nf < 4; ++nf) { \
      const int c_ = wn * 64 + nf * 16 + l15; \
      const char* p_ = smem + 65536 + (slot) * 32768 + c_ * 128; \
      b[nf * 2 + 0] = *(const short8*)(p_ + koff0); \
      b[nf * 2 + 1] = *(const short8*)(p_ + koff1); \
    } \
  } while (0)

// 32 MFMA: one qm (4 mf) x all 4 nf x 2 k-halves
#define MFMA_QM(qm_) do { \
    __builtin_amdgcn_s_setprio(1); \
    _Pragma("unroll") \
    for (int mf = 0; mf < 4; ++mf) \
      _Pragma("unroll") \
      for (int nf = 0; nf < 4; ++nf) { \
        acc[(qm_) * 4 + mf][nf] = __builtin_amdgcn_mfma_f32_16x16x32_bf16( \
            a[mf * 2 + 0], b[nf * 2 + 0], acc[(qm_) * 4 + mf][nf], 0, 0, 0); \
        acc[(qm_) * 4 + mf][nf] = __builtin_amdgcn_mfma_f32_16x16x32_bf16( \
            a[mf * 2 + 1], b[nf * 2 + 1], acc[(qm_) * 4 + mf][nf], 0, 0, 0); \
      } \
    __builtin_amdgcn_s_setprio(0); \
  } while (0)

#define BAR() do { asm volatile("s_barrier" ::: "memory"); __builtin_amdgcn_sched_barrier(0); } while (0)
#define VMCNT4() asm volatile("s_waitcnt vmcnt(4)" ::: "memory")
#define VMCNT0() asm volatile("s_waitcnt vmcnt(0)" ::: "memory")

  // ---- prologue: K0 full (B0,A0) + K1's B half-tiles (12 loads/thread)
  STAGE_B(0, 0, 0); STAGE_B(0, 1, 0);
  STAGE_A(0, 0, 0); STAGE_A(0, 1, 0);
  STAGE_B(1, 0, 1); STAGE_B(1, 1, 1);
  VMCNT4();   // oldest 8 (K0) landed; K1 B's may fly
  BAR();

  for (int i = 0; i < NI; ++i) {
    const int t2 = 2 * i + 2, t3 = 2 * i + 3;
    const bool pf = (i < NI - 1);
    // ph0': slot0 qm0 (all nf) | stage A slot1 (K 2i+1)
    READ_A(0, 0); READ_B_ALL(0);
    STAGE_A(1, 0, 2 * i + 1); STAGE_A(1, 1, 2 * i + 1);
    BAR(); MFMA_QM(0); BAR();
    // ph1': slot0 qm1 | stage B slot0 (K 2i+2) | vmcnt guards slot1 (B1+A1 of K 2i+1)
    READ_A(0, 1);
    if (pf) { STAGE_B(0, 0, t2); STAGE_B(0, 1, t2); }
    BAR(); MFMA_QM(1);
    if (pf) { VMCNT4(); } else { VMCNT0(); }
    BAR();
    // ph2': slot1 qm0 | stage A slot0 (K 2i+2)
    READ_A(1, 0); READ_B_ALL(1);
    if (pf) { STAGE_A(0, 0, t2); STAGE_A(0, 1, t2); }
    BAR(); MFMA_QM(0); BAR();
    // ph3': slot1 qm1 | stage B slot1 (K 2i+3) | vmcnt guards slot0 (B0+A0 of K 2i+2)
    READ_A(1, 1);
    if (pf) { STAGE_B(1, 0, t3); STAGE_B(1, 1, t3); }
    BAR(); MFMA_QM(1);
    if (pf) { VMCNT4(); }
    BAR();
  }

#undef STAGE_A
#undef STAGE_B
#undef READ_A
#undef READ_B_ALL
#undef MFMA_QM
#undef BAR
#undef VMCNT4
#undef VMCNT0

  // ---- epilogue: bias + silu (C/D: col=lane&15, row=(lane>>4)*4+rr)
  #pragma unroll
  for (int nr = 0; nr < 4; ++nr) {
    const int col = col0 + wn * 64 + nr * 16 + l15;
    const float bv = bias[col * 16 + e];
    #pragma unroll
    for (int mr = 0; mr < 8; ++mr) {
      const int row = row0 + wm * 128 + mr * 16 + ((lane >> 4) << 2);
      const f32x4 v = acc[mr][nr];
      #pragma unroll
      for (int rr = 0; rr < 4; ++rr) {
        const float y = v[rr] + bv;
        out[(size_t)(row + rr) * DOUT + col] = y * (1.0f / (1.0f + __expf(-y)));
      }
    }
  }
}

// ---------------- R2 fallback: 128^2 single-buffer gload_lds GEMM ----------------
__global__ __launch_bounds__(256, 4)
void moe_gemm_s(const unsigned short* __restrict__ xs, const unsigned short* __restrict__ Wt,
                const float* __restrict__ bias, float* __restrict__ out) {
  __shared__ unsigned short sA[128 * 64];
  __shared__ unsigned short sB[128 * 64];

  const int bid = blockIdx.x;
  const int swz = (bid & 7) * 1024 + (bid >> 3);
  const int e  = swz >> 9;
  const int mb = (swz >> 4) & 31;
  const int nb = swz & 15;
  const int row0 = e * NPE + mb * 128;
  const int col0 = nb * 128;

  const int tid = threadIdx.x;
  const int lane = tid & 63;
  const int w = tid >> 6;
  const int wm = w >> 1, wn = w & 1;

  const char* xa = (const char*)xs + (size_t)row0 * (DIN * 2);
  const char* wb = (const char*)(Wt + (size_t)e * (DOUT * DIN) + (size_t)col0 * DIN);
  const int lrow8 = lane >> 3;
  const int lk = (lane & 7) * 16;

  f32x4 acc[4][4];
  #pragma unroll
  for (int i = 0; i < 4; ++i)
    #pragma unroll
    for (int j = 0; j < 4; ++j) acc[i][j] = (f32x4){0.f, 0.f, 0.f, 0.f};

  for (int kt = 0; kt < NKT; ++kt) {
    __syncthreads();
    #pragma unroll
    for (int i = 0; i < 4; ++i) {
      const int c = w * 4 + i;
      const int r = c * 8 + lrow8;
      gload_lds16(xa + (size_t)r * (DIN * 2) + kt * 128 + lk, (char*)sA + c * 1024);
      gload_lds16(wb + (size_t)r * (DIN * 2) + kt * 128 + lk, (char*)sB + c * 1024);
    }
    __syncthreads();
    #pragma unroll
    for (int ks = 0; ks < 2; ++ks) {
      short8 av[4], bv[4];
      const int hib = ks * 64 + ((lane >> 4) << 4);
      #pragma unroll
      for (int mf = 0; mf < 4; ++mf) {
        const int r = wm * 64 + mf * 16 + (lane & 15);
        av[mf] = *(const short8*)((const char*)sA + r * 128 + (hib ^ ((r & 7) << 4)));
      }
      #pragma unroll
      for (int nf = 0; nf < 4; ++nf) {
        const int o = wn * 64 + nf * 16 + (lane & 15);
        bv[nf] = *(const short8*)((const char*)sB + o * 128 + (hib ^ ((o & 7) << 4)));
      }
      #pragma unroll
      for (int mf = 0; mf < 4; ++mf)
        #pragma unroll
        for (int nf = 0; nf < 4; ++nf)
          acc[mf][nf] = __builtin_amdgcn_mfma_f32_16x16x32_bf16(av[mf], bv[nf], acc[mf][nf], 0, 0, 0);
    }
  }

  #pragma unroll
  for (int nf = 0; nf < 4; ++nf) {
    const int col = col0 + wn * 64 + nf * 16 + (lane & 15);
    const float bv = bias[col * 16 + e];
    #pragma unroll
    for (int mf = 0; mf < 4; ++mf) {
      const int row = row0 + wm * 64 + mf * 16 + ((lane >> 4) << 2);
      const f32x4 v = acc[mf][nf];
      #pragma unroll
      for (int r = 0; r < 4; ++r) {
        const float y = v[r] + bv;
        out[(size_t)(row + r) * DOUT + col] = y * (1.0f / (1.0f + __expf(-y)));
      }
    }
  }
}

// ---------------- R1 fallback (ws < 192 MiB) ----------------
#define BM 128
#define BN 128
#define BK 64
#define LDA 72

__global__ void prep_w_plain(const float* __restrict__ W, unsigned short* __restrict__ Wt) {
  __shared__ unsigned short tile[16][32][33];
  const int k0 = (blockIdx.x >> 6) * 32;
  const int o0 = (blockIdx.x & 63) * 32;
  const int tid = threadIdx.x;

  for (int p = tid; p < 1024; p += 256) {
    const int k = p >> 5, o = p & 31;
    const float4* src = (const float4*)(W + ((size_t)(k0 + k) * DOUT + (o0 + o)) * 16);
    float4 v0 = src[0], v1 = src[1], v2 = src[2], v3 = src[3];
    const float vv[16] = {v0.x, v0.y, v0.z, v0.w, v1.x, v1.y, v1.z, v1.w,
                          v2.x, v2.y, v2.z, v2.w, v3.x, v3.y, v3.z, v3.w};
    #pragma unroll
    for (int e = 0; e < 16; ++e) tile[e][k][o] = f2bf(vv[e]);
  }
  __syncthreads();
  for (int c = tid; c < 2048; c += 256) {
    const int kc = c & 3, o = (c >> 2) & 31, e = c >> 7;
    unsigned short vals[8];
    #pragma unroll
    for (int j = 0; j < 8; ++j) vals[j] = tile[e][kc * 8 + j][o];
    uint4 wv;
    wv.x = vals[0] | ((unsigned)vals[1] << 16);
    wv.y = vals[2] | ((unsigned)vals[3] << 16);
    wv.z = vals[4] | ((unsigned)vals[5] << 16);
    wv.w = vals[6] | ((unsigned)vals[7] << 16);
    *(uint4*)(Wt + (size_t)e * (DOUT * DIN) + (size_t)(o0 + o) * DIN + k0 + kc * 8) = wv;
  }
}

__global__ __launch_bounds__(256, 2)
void moe_gemm_f32a(const float* __restrict__ x, const unsigned short* __restrict__ Wt,
                   const float* __restrict__ bias, float* __restrict__ out) {
  __shared__ unsigned short sA[2][BM * LDA];
  __shared__ unsigned short sB[2][BN * BK];

  const int bid = blockIdx.x;
  const int swz = (bid & 7) * 1024 + (bid >> 3);
  const int e  = swz >> 9;
  const int mb = (swz >> 4) & 31;
  const int nb = swz & 15;
  const int row0 = e * NPE + mb * BM;
  const int col0 = nb * BN;

  const int tid = threadIdx.x;
  const int lane = tid & 63;
  const int w = tid >> 6;
  const int wm = w >> 1, wn = w & 1;

  const float* xb = x + (size_t)row0 * DIN;
  const char* wbase = (const char*)(Wt + (size_t)e * (DOUT * DIN) + (size_t)col0 * DIN);

  f32x4 acc[4][4];
  #pragma unroll
  for (int i = 0; i < 4; ++i)
    #pragma unroll
    for (int j = 0; j < 4; ++j) acc[i][j] = (f32x4){0.f, 0.f, 0.f, 0.f};

  float4 ar[8];

  #pragma unroll
  for (int i = 0; i < 8; ++i) {
    const int c = tid + i * 256;
    ar[i] = *(const float4*)(xb + (size_t)(c >> 4) * DIN + (c & 15) * 4);
  }
  #pragma unroll
  for (int j = 0; j < 4; ++j) {
    const int ch = w * 4 + j;
    const int L = ch * 1024 + lane * 16;
    const int o_l = L >> 7;
    const int kb = (L & 127) ^ ((o_l & 7) << 4);
    gload_lds16(wbase + (size_t)o_l * (DIN * 2) + kb, (char*)(&sB[0][0]) + ch * 1024);
  }
  #pragma unroll
  for (int i = 0; i < 8; ++i) {
    const int c = tid + i * 256;
    uint2 hv;
    hv.x = f2bf(ar[i].x) | ((unsigned)f2bf(ar[i].y) << 16);
    hv.y = f2bf(ar[i].z) | ((unsigned)f2bf(ar[i].w) << 16);
    *(uint2*)((char*)(&sA[0][0]) + (c >> 4) * (LDA * 2) + (c & 15) * 8) = hv;
  }
  __syncthreads();

  int cur = 0;
  for (int kt = 0; kt < NKT; ++kt) {
    const int nxt = cur ^ 1;
    if (kt + 1 < NKT) {
      #pragma unroll
      for (int i = 0; i < 8; ++i) {
        const int c = tid + i * 256;
        ar[i] = *(const float4*)(xb + (size_t)(c >> 4) * DIN + (kt + 1) * BK + (c & 15) * 4);
      }
      #pragma unroll
      for (int j = 0; j < 4; ++j) {
        const int ch = w * 4 + j;
        const int L = ch * 1024 + lane * 16;
        const int o_l = L >> 7;
        const int kb = (L & 127) ^ ((o_l & 7) << 4);
        gload_lds16(wbase + (size_t)o_l * (DIN * 2) + (size_t)(kt + 1) * (BK * 2) + kb,
                    (char*)(&sB[nxt][0]) + ch * 1024);
      }
    }
    const char* Ab = (const char*)(&sA[cur][0]);
    const char* Bb = (const char*)(&sB[cur][0]);
    #pragma unroll
    for (int ks = 0; ks < 2; ++ks) {
      short8 av[4], bv[4];
      #pragma unroll
      for (int mf = 0; mf < 4; ++mf) {
        const int r = wm * 64 + mf * 16 + (lane & 15);
        av[mf] = *(const short8*)(Ab + r * (LDA * 2) + ks * 64 + ((lane >> 4) << 4));
      }
      #pragma unroll
      for (int nf = 0; nf < 4; ++nf) {
        const int o = wn * 64 + nf * 16 + (lane & 15);
        const int kb = (ks * 64 + ((lane >> 4) << 4)) ^ ((o & 7) << 4);
        bv[nf] = *(const short8*)(Bb + o * 128 + kb);
      }
      #pragma unroll
      for (int mf = 0; mf < 4; ++mf)
        #pragma unroll
        for (int nf = 0; nf < 4; ++nf)
          acc[mf][nf] = __builtin_amdgcn_mfma_f32_16x16x32_bf16(av[mf], bv[nf], acc[mf][nf], 0, 0, 0);
    }
    if (kt + 1 < NKT) {
      #pragma unroll
      for (int i = 0; i < 8; ++i) {
        const int c = tid + i * 256;
        uint2 hv;
        hv.x = f2bf(ar[i].x) | ((unsigned)f2bf(ar[i].y) << 16);
        hv.y = f2bf(ar[i].z) | ((unsigned)f2bf(ar[i].w) << 16);
        *(uint2*)((char*)(&sA[nxt][0]) + (c >> 4) * (LDA * 2) + (c & 15) * 8) = hv;
      }
    }
    __syncthreads();
    cur = nxt;
  }

  #pragma unroll
  for (int nf = 0; nf < 4; ++nf) {
    const int col = col0 + wn * 64 + nf * 16 + (lane & 15);
    const float bv = bias[col * 16 + e];
    #pragma unroll
    for (int mf = 0; mf < 4; ++mf) {
      const int row = row0 + wm * 64 + mf * 16 + ((lane >> 4) << 2);
      const f32x4 v = acc[mf][nf];
      #pragma unroll
      for (int r = 0; r < 4; ++r) {
        const float y = v[r] + bv;
        out[(size_t)(row + r) * DOUT + col] = y * (1.0f / (1.0f + __expf(-y)));
      }
    }
  }
}

extern "C" void kernel_launch(void* const* d_in, const int* in_sizes, int n_in,
                              void* d_out, int out_size, void* d_ws, size_t ws_size,
                              hipStream_t stream) {
  const float* x    = (const float*)d_in[0];
  // d_in[1] = expert_ids_sorted (int32) — equal split is static, unused.
  const float* W    = (const float*)d_in[2];
  const float* bias = (const float*)d_in[3];
  float* out = (float*)d_out;

  const size_t wt_bytes = (size_t)E_ * DOUT * DIN * 2;        // 64 MiB
  const size_t xs_bytes = (size_t)NTOK * DIN * 2;             // 128 MiB

  unsigned short* Wt = (unsigned short*)d_ws;

  if (ws_size >= wt_bytes + xs_bytes) {
    unsigned short* xsw = (unsigned short*)((char*)d_ws + wt_bytes);
    prep_fused<<<4096, 256, 0, stream>>>(x, xsw, W, Wt);
    static const bool lds_ok =
        (hipFuncSetAttribute(reinterpret_cast<const void*>(moe_gemm4p),
                             hipFuncAttributeMaxDynamicSharedMemorySize, 131072) == hipSuccess);
    if (lds_ok) {
      moe_gemm4p<<<2048, 512, 131072, stream>>>(xsw, Wt, bias, out);
    } else {
      moe_gemm_s<<<8192, 256, 0, stream>>>(xsw, Wt, bias, out);
    }
  } else {
    prep_w_plain<<<2048, 256, 0, stream>>>(W, Wt);
    moe_gemm_f32a<<<8192, 256, 0, stream>>>(x, Wt, bias, out);
  }
}

// Round 6
// 413.953 us; speedup vs baseline: 1.3073x; 1.3073x over previous
//
#include <hip/hip_runtime.h>
#include <hip/hip_bf16.h>

// MoE expert collection: out = silu(x @ W_e + b_e), 16 experts, equal token split.
// x: [65536][1024] f32, W: [1024][2048][16] f32, b: [2048][16] f32, out: [65536][2048] f32.
//
// R6 = R5 with compile fix (nontemporal loads need ext_vector_type pointers, not
// HIP_vector_type). R3's proven 256x256x64 8-phase schedule + nt prep loads +
// nt epilogue stores + rcp silu + lgkmcnt(8) partial wait in 12-read phases.
// Fallbacks: R2 kernel (if 128KB LDS attr fails), R1 kernel (if ws < 192 MiB).

#define E_ 16
#define DIN 1024
#define DOUT 2048
#define NTOK 65536
#define NPE (NTOK / E_)
#define NKT (DIN / 64)    // 16 K-tiles of 64
#define NI (NKT / 2)      // 8 iterations, 2 K-tiles each

typedef __attribute__((ext_vector_type(8))) short short8;
typedef __attribute__((ext_vector_type(4))) float f32x4;
typedef __attribute__((ext_vector_type(4))) unsigned int u32x4;

__device__ __forceinline__ unsigned short f2bf(float f) {
  union { float f; unsigned int u; } v; v.f = f;
  unsigned int u = v.u;
  return (unsigned short)((u + 0x7fffu + ((u >> 16) & 1u)) >> 16);  // RNE
}

__device__ __forceinline__ void gload_lds16(const void* g, void* l) {
  __builtin_amdgcn_global_load_lds(
      (const __attribute__((address_space(1))) void*)g,
      (__attribute__((address_space(3))) void*)l, 16, 0, 0);
}

// ---------------- prep_x: x [m][k] f32 -> xs [m][k] bf16, 16B-blocks XOR-swizzled by (m&7)
__global__ __launch_bounds__(256)
void prep_x(const float* __restrict__ x, unsigned short* __restrict__ xs) {
  const int nunits = NTOK * (DIN / 8);
  for (int u = blockIdx.x * 256 + threadIdx.x; u < nunits; u += gridDim.x * 256) {
    const int m = u >> 7;
    const int j = u & 127;
    const f32x4* src = (const f32x4*)(x + (size_t)m * DIN + j * 8);
    const f32x4 a = __builtin_nontemporal_load(src);       // single-use: skip cache fill
    const f32x4 b = __builtin_nontemporal_load(src + 1);
    u32x4 v;
    v.x = f2bf(a.x) | ((unsigned)f2bf(a.y) << 16);
    v.y = f2bf(a.z) | ((unsigned)f2bf(a.w) << 16);
    v.z = f2bf(b.x) | ((unsigned)f2bf(b.y) << 16);
    v.w = f2bf(b.z) | ((unsigned)f2bf(b.w) << 16);
    const int js = (j & ~7) | ((j & 7) ^ (m & 7));
    *(u32x4*)(xs + (size_t)m * DIN + js * 8) = v;          // re-read by GEMM: cacheable
  }
}

// ---------------- prep_w: W [k][o][e] f32 -> Wt [e][o][k] bf16 (optionally pre-swizzled)
template <bool SWZ>
__global__ __launch_bounds__(256)
void prep_w(const float* __restrict__ W, unsigned short* __restrict__ Wt) {
  __shared__ unsigned short tile[16][32][33];
  const int k0 = (blockIdx.x >> 6) * 32;
  const int o0 = (blockIdx.x & 63) * 32;
  const int tid = threadIdx.x;

  for (int p = tid; p < 1024; p += 256) {
    const int k = p >> 5, o = p & 31;
    const f32x4* src = (const f32x4*)(W + ((size_t)(k0 + k) * DOUT + (o0 + o)) * 16);
    f32x4 v0 = __builtin_nontemporal_load(src);
    f32x4 v1 = __builtin_nontemporal_load(src + 1);
    f32x4 v2 = __builtin_nontemporal_load(src + 2);
    f32x4 v3 = __builtin_nontemporal_load(src + 3);
    const float vv[16] = {v0.x, v0.y, v0.z, v0.w, v1.x, v1.y, v1.z, v1.w,
                          v2.x, v2.y, v2.z, v2.w, v3.x, v3.y, v3.z, v3.w};
    #pragma unroll
    for (int e = 0; e < 16; ++e) tile[e][k][o] = f2bf(vv[e]);
  }
  __syncthreads();
  for (int c = tid; c < 2048; c += 256) {
    const int kc = c & 3, o = (c >> 2) & 31, e = c >> 7;
    unsigned short vals[8];
    #pragma unroll
    for (int j = 0; j < 8; ++j) vals[j] = tile[e][kc * 8 + j][o];
    u32x4 wv;
    wv.x = vals[0] | ((unsigned)vals[1] << 16);
    wv.y = vals[2] | ((unsigned)vals[3] << 16);
    wv.z = vals[4] | ((unsigned)vals[5] << 16);
    wv.w = vals[6] | ((unsigned)vals[7] << 16);
    const int jb = (k0 >> 3) + kc;
    const int jbs = SWZ ? ((jb & ~7) | ((jb & 7) ^ (o & 7))) : jb;
    *(u32x4*)(Wt + (size_t)e * (DOUT * DIN) + (size_t)(o0 + o) * DIN + jbs * 8) = wv;
  }
}

// ---------------- R6 main: 256^2 8-phase GEMM (R3 schedule) ----------------
__global__ __launch_bounds__(512, 2)
void moe_gemm8(const unsigned short* __restrict__ xs, const unsigned short* __restrict__ Wt,
               const float* __restrict__ bias, float* __restrict__ out) {
  extern __shared__ char smem[];   // 128 KiB: A slots [0,64K), B slots [64K,128K)

  const int bid = blockIdx.x;
  const int swz = (bid & 7) * 256 + (bid >> 3);   // bijective: 2048 % 8 == 0
  const int e  = swz >> 7;          // 128 blocks/expert
  const int mb = (swz >> 3) & 15;   // 16 row-tiles
  const int nb = swz & 7;           // 8 col-tiles
  const int row0 = e * NPE + mb * 256;
  const int col0 = nb * 256;

  const int tid = threadIdx.x;
  const int lane = tid & 63;
  const int w = tid >> 6;
  const int wm = w >> 2, wn = w & 3;   // 2M x 4N wave grid, 128x64 out per wave
  const int l15 = lane & 15;

  const char* xa  = (const char*)xs + (size_t)row0 * (DIN * 2);
  const char* wbg = (const char*)(Wt + (size_t)e * (DOUT * DIN) + (size_t)col0 * DIN);

  const int crow0 = w * 16 + (lane >> 3);
  const int kb16  = (lane & 7) * 16;
  const int dch0  = w * 2048;

  const int hi16  = (lane >> 4) << 4;
  const int sw7   = (lane & 7) << 4;
  const int koff0 = (0   | hi16) ^ sw7;
  const int koff1 = (64  | hi16) ^ sw7;

  f32x4 acc[8][4];
  #pragma unroll
  for (int i = 0; i < 8; ++i)
    #pragma unroll
    for (int j = 0; j < 4; ++j) acc[i][j] = (f32x4){0.f, 0.f, 0.f, 0.f};

  short8 a[8], b[8];

#define STAGE_A(slot, half, kt) do { \
    gload_lds16(xa + (size_t)((half) * 128 + crow0) * (DIN * 2) + (kt) * 128 + kb16, \
                smem + (slot) * 32768 + (half) * 16384 + dch0); \
    gload_lds16(xa + (size_t)((half) * 128 + crow0 + 8) * (DIN * 2) + (kt) * 128 + kb16, \
                smem + (slot) * 32768 + (half) * 16384 + dch0 + 1024); \
  } while (0)

#define STAGE_B(slot, half, kt) do { \
    gload_lds16(wbg + (size_t)((half) * 128 + crow0) * (DIN * 2) + (kt) * 128 + kb16, \
                smem + 65536 + (slot) * 32768 + (half) * 16384 + dch0); \
    gload_lds16(wbg + (size_t)((half) * 128 + crow0 + 8) * (DIN * 2) + (kt) * 128 + kb16, \
                smem + 65536 + (slot) * 32768 + (half) * 16384 + dch0 + 1024); \
  } while (0)

#define READ_A(slot, qm_) do { \
    _Pragma("unroll") \
    for (int mf = 0; mf < 4; ++mf) { \
      const int r_ = wm * 128 + (qm_) * 64 + mf * 16 + l15; \
      const char* p_ = smem + (slot) * 32768 + r_ * 128; \
      a[mf * 2 + 0] = *(const short8*)(p_ + koff0); \
      a[mf * 2 + 1] = *(const short8*)(p_ + koff1); \
    } \
  } while (0)

#define READ_B(slot, qn_) do { \
    _Pragma("unroll") \
    for (int nf = 0; nf < 2; ++nf) { \
      const int c_ = wn * 64 + (qn_) * 32 + nf * 16 + l15; \
      const char* p_ = smem + 65536 + (slot) * 32768 + c_ * 128; \
      b[(qn_) * 4 + nf * 2 + 0] = *(const short8*)(p_ + koff0); \
      b[(qn_) * 4 + nf * 2 + 1] = *(const short8*)(p_ + koff1); \
    } \
  } while (0)

#define MFMA_Q(qm_, qn_) do { \
    __builtin_amdgcn_s_setprio(1); \
    _Pragma("unroll") \
    for (int mf = 0; mf < 4; ++mf) \
      _Pragma("unroll") \
      for (int nf = 0; nf < 2; ++nf) { \
        acc[(qm_) * 4 + mf][(qn_) * 2 + nf] = __builtin_amdgcn_mfma_f32_16x16x32_bf16( \
            a[mf * 2 + 0], b[((qn_) * 2 + nf) * 2 + 0], acc[(qm_) * 4 + mf][(qn_) * 2 + nf], 0, 0, 0); \
        acc[(qm_) * 4 + mf][(qn_) * 2 + nf] = __builtin_amdgcn_mfma_f32_16x16x32_bf16( \
            a[mf * 2 + 1], b[((qn_) * 2 + nf) * 2 + 1], acc[(qm_) * 4 + mf][(qn_) * 2 + nf], 0, 0, 0); \
      } \
    __builtin_amdgcn_s_setprio(0); \
  } while (0)

#define BAR() do { asm volatile("s_barrier" ::: "memory"); __builtin_amdgcn_sched_barrier(0); } while (0)
#define LGKM8() asm volatile("s_waitcnt lgkmcnt(8)" ::: "memory")
#define VMCNT4() asm volatile("s_waitcnt vmcnt(4)" ::: "memory")
#define VMCNT0() asm volatile("s_waitcnt vmcnt(0)" ::: "memory")

  // ---- prologue: K-tile 0 fully + K-tile 1's B halves (12 loads/thread)
  STAGE_A(0, 0, 0); STAGE_A(0, 1, 0); STAGE_B(0, 0, 0); STAGE_B(0, 1, 0);
  STAGE_B(1, 0, 1); STAGE_B(1, 1, 1);
  VMCNT4();   // K0 (oldest 8) complete; K1 B's (4) may fly
  BAR();

  for (int i = 0; i < NI; ++i) {
    const int t2 = 2 * i + 2, t3 = 2 * i + 3;
    const bool pf = (i < NI - 1);
    // ph0: slot0 Q(0,0) | stage A-half0 slot1 (K 2i+1)   [12 ds_reads -> lgkm(8) throttle]
    READ_A(0, 0); READ_B(0, 0);
    STAGE_A(1, 0, 2 * i + 1);
    LGKM8();
    BAR(); MFMA_Q(0, 0); BAR();
    // ph1: slot0 Q(0,1) | stage A-half1 slot1 (K 2i+1)
    READ_B(0, 1);
    STAGE_A(1, 1, 2 * i + 1);
    BAR(); MFMA_Q(0, 1); BAR();
    // ph2: slot0 Q(1,1) | stage B-half0 slot0 (K 2i+2)   [B slot0 free after ph1]
    READ_A(0, 1);
    if (pf) STAGE_B(0, 0, t2);
    BAR(); MFMA_Q(1, 1); BAR();
    // ph3: slot0 Q(1,0) | stage B-half1 slot0 | vmcnt guards slot1 (K 2i+1)
    if (pf) STAGE_B(0, 1, t2);
    BAR(); MFMA_Q(1, 0);
    if (pf) { VMCNT4(); } else { VMCNT0(); }
    BAR();
    // ph4: slot1 Q(0,0) | stage A-half0 slot0 (K 2i+2)   [A slot0 free after ph2]
    READ_A(1, 0); READ_B(1, 0);
    if (pf) STAGE_A(0, 0, t2);
    LGKM8();
    BAR(); MFMA_Q(0, 0); BAR();
    // ph5: slot1 Q(0,1) | stage A-half1 slot0
    READ_B(1, 1);
    if (pf) STAGE_A(0, 1, t2);
    BAR(); MFMA_Q(0, 1); BAR();
    // ph6: slot1 Q(1,1) | stage B-half0 slot1 (K 2i+3)   [B slot1 free after ph5]
    READ_A(1, 1);
    if (pf) STAGE_B(1, 0, t3);
    BAR(); MFMA_Q(1, 1); BAR();
    // ph7: slot1 Q(1,0) | stage B-half1 slot1 | vmcnt guards slot0 (K 2i+2)
    if (pf) STAGE_B(1, 1, t3);
    BAR(); MFMA_Q(1, 0);
    if (pf) { VMCNT4(); }
    BAR();
  }

#undef STAGE_A
#undef STAGE_B
#undef READ_A
#undef READ_B
#undef MFMA_Q
#undef BAR
#undef LGKM8
#undef VMCNT4
#undef VMCNT0

  // ---- epilogue: bias + silu (C/D: col=lane&15, row=(lane>>4)*4+rr), nt stores
  #pragma unroll
  for (int nr = 0; nr < 4; ++nr) {
    const int col = col0 + wn * 64 + nr * 16 + l15;
    const float bv = bias[col * 16 + e];
    #pragma unroll
    for (int mr = 0; mr < 8; ++mr) {
      const int row = row0 + wm * 128 + mr * 16 + ((lane >> 4) << 2);
      const f32x4 v = acc[mr][nr];
      #pragma unroll
      for (int rr = 0; rr < 4; ++rr) {
        const float y = v[rr] + bv;
        const float s = y * __builtin_amdgcn_rcpf(1.0f + __expf(-y));
        __builtin_nontemporal_store(s, &out[(size_t)(row + rr) * DOUT + col]);
      }
    }
  }
}

// ---------------- R2 fallback: 128^2 single-buffer gload_lds GEMM ----------------
__global__ __launch_bounds__(256, 4)
void moe_gemm_s(const unsigned short* __restrict__ xs, const unsigned short* __restrict__ Wt,
                const float* __restrict__ bias, float* __restrict__ out) {
  __shared__ unsigned short sA[128 * 64];
  __shared__ unsigned short sB[128 * 64];

  const int bid = blockIdx.x;
  const int swz = (bid & 7) * 1024 + (bid >> 3);
  const int e  = swz >> 9;
  const int mb = (swz >> 4) & 31;
  const int nb = swz & 15;
  const int row0 = e * NPE + mb * 128;
  const int col0 = nb * 128;

  const int tid = threadIdx.x;
  const int lane = tid & 63;
  const int w = tid >> 6;
  const int wm = w >> 1, wn = w & 1;

  const char* xa = (const char*)xs + (size_t)row0 * (DIN * 2);
  const char* wb = (const char*)(Wt + (size_t)e * (DOUT * DIN) + (size_t)col0 * DIN);
  const int lrow8 = lane >> 3;
  const int lk = (lane & 7) * 16;

  f32x4 acc[4][4];
  #pragma unroll
  for (int i = 0; i < 4; ++i)
    #pragma unroll
    for (int j = 0; j < 4; ++j) acc[i][j] = (f32x4){0.f, 0.f, 0.f, 0.f};

  for (int kt = 0; kt < NKT; ++kt) {
    __syncthreads();
    #pragma unroll
    for (int i = 0; i < 4; ++i) {
      const int c = w * 4 + i;
      const int r = c * 8 + lrow8;
      gload_lds16(xa + (size_t)r * (DIN * 2) + kt * 128 + lk, (char*)sA + c * 1024);
      gload_lds16(wb + (size_t)r * (DIN * 2) + kt * 128 + lk, (char*)sB + c * 1024);
    }
    __syncthreads();
    #pragma unroll
    for (int ks = 0; ks < 2; ++ks) {
      short8 av[4], bv[4];
      const int hib = ks * 64 + ((lane >> 4) << 4);
      #pragma unroll
      for (int mf = 0; mf < 4; ++mf) {
        const int r = wm * 64 + mf * 16 + (lane & 15);
        av[mf] = *(const short8*)((const char*)sA + r * 128 + (hib ^ ((r & 7) << 4)));
      }
      #pragma unroll
      for (int nf = 0; nf < 4; ++nf) {
        const int o = wn * 64 + nf * 16 + (lane & 15);
        bv[nf] = *(const short8*)((const char*)sB + o * 128 + (hib ^ ((o & 7) << 4)));
      }
      #pragma unroll
      for (int mf = 0; mf < 4; ++mf)
        #pragma unroll
        for (int nf = 0; nf < 4; ++nf)
          acc[mf][nf] = __builtin_amdgcn_mfma_f32_16x16x32_bf16(av[mf], bv[nf], acc[mf][nf], 0, 0, 0);
    }
  }

  #pragma unroll
  for (int nf = 0; nf < 4; ++nf) {
    const int col = col0 + wn * 64 + nf * 16 + (lane & 15);
    const float bv = bias[col * 16 + e];
    #pragma unroll
    for (int mf = 0; mf < 4; ++mf) {
      const int row = row0 + wm * 64 + mf * 16 + ((lane >> 4) << 2);
      const f32x4 v = acc[mf][nf];
      #pragma unroll
      for (int r = 0; r < 4; ++r) {
        const float y = v[r] + bv;
        out[(size_t)(row + r) * DOUT + col] = y * (1.0f / (1.0f + __expf(-y)));
      }
    }
  }
}

// ---------------- R1 fallback (ws < 192 MiB) ----------------
#define BM 128
#define BN 128
#define BK 64
#define LDA 72

__global__ void prep_w_plain(const float* __restrict__ W, unsigned short* __restrict__ Wt) {
  __shared__ unsigned short tile[16][32][33];
  const int k0 = (blockIdx.x >> 6) * 32;
  const int o0 = (blockIdx.x & 63) * 32;
  const int tid = threadIdx.x;

  for (int p = tid; p < 1024; p += 256) {
    const int k = p >> 5, o = p & 31;
    const f32x4* src = (const f32x4*)(W + ((size_t)(k0 + k) * DOUT + (o0 + o)) * 16);
    f32x4 v0 = src[0], v1 = src[1], v2 = src[2], v3 = src[3];
    const float vv[16] = {v0.x, v0.y, v0.z, v0.w, v1.x, v1.y, v1.z, v1.w,
                          v2.x, v2.y, v2.z, v2.w, v3.x, v3.y, v3.z, v3.w};
    #pragma unroll
    for (int e = 0; e < 16; ++e) tile[e][k][o] = f2bf(vv[e]);
  }
  __syncthreads();
  for (int c = tid; c < 2048; c += 256) {
    const int kc = c & 3, o = (c >> 2) & 31, e = c >> 7;
    unsigned short vals[8];
    #pragma unroll
    for (int j = 0; j < 8; ++j) vals[j] = tile[e][kc * 8 + j][o];
    u32x4 wv;
    wv.x = vals[0] | ((unsigned)vals[1] << 16);
    wv.y = vals[2] | ((unsigned)vals[3] << 16);
    wv.z = vals[4] | ((unsigned)vals[5] << 16);
    wv.w = vals[6] | ((unsigned)vals[7] << 16);
    *(u32x4*)(Wt + (size_t)e * (DOUT * DIN) + (size_t)(o0 + o) * DIN + k0 + kc * 8) = wv;
  }
}

__global__ __launch_bounds__(256, 2)
void moe_gemm_f32a(const float* __restrict__ x, const unsigned short* __restrict__ Wt,
                   const float* __restrict__ bias, float* __restrict__ out) {
  __shared__ unsigned short sA[2][BM * LDA];
  __shared__ unsigned short sB[2][BN * BK];

  const int bid = blockIdx.x;
  const int swz = (bid & 7) * 1024 + (bid >> 3);
  const int e  = swz >> 9;
  const int mb = (swz >> 4) & 31;
  const int nb = swz & 15;
  const int row0 = e * NPE + mb * BM;
  const int col0 = nb * BN;

  const int tid = threadIdx.x;
  const int lane = tid & 63;
  const int w = tid >> 6;
  const int wm = w >> 1, wn = w & 1;

  const float* xb = x + (size_t)row0 * DIN;
  const char* wbase = (const char*)(Wt + (size_t)e * (DOUT * DIN) + (size_t)col0 * DIN);

  f32x4 acc[4][4];
  #pragma unroll
  for (int i = 0; i < 4; ++i)
    #pragma unroll
    for (int j = 0; j < 4; ++j) acc[i][j] = (f32x4){0.f, 0.f, 0.f, 0.f};

  f32x4 ar[8];

  #pragma unroll
  for (int i = 0; i < 8; ++i) {
    const int c = tid + i * 256;
    ar[i] = *(const f32x4*)(xb + (size_t)(c >> 4) * DIN + (c & 15) * 4);
  }
  #pragma unroll
  for (int j = 0; j < 4; ++j) {
    const int ch = w * 4 + j;
    const int L = ch * 1024 + lane * 16;
    const int o_l = L >> 7;
    const int kb = (L & 127) ^ ((o_l & 7) << 4);
    gload_lds16(wbase + (size_t)o_l * (DIN * 2) + kb, (char*)(&sB[0][0]) + ch * 1024);
  }
  #pragma unroll
  for (int i = 0; i < 8; ++i) {
    const int c = tid + i * 256;
    uint2 hv;
    hv.x = f2bf(ar[i].x) | ((unsigned)f2bf(ar[i].y) << 16);
    hv.y = f2bf(ar[i].z) | ((unsigned)f2bf(ar[i].w) << 16);
    *(uint2*)((char*)(&sA[0][0]) + (c >> 4) * (LDA * 2) + (c & 15) * 8) = hv;
  }
  __syncthreads();

  int cur = 0;
  for (int kt = 0; kt < NKT; ++kt) {
    const int nxt = cur ^ 1;
    if (kt + 1 < NKT) {
      #pragma unroll
      for (int i = 0; i < 8; ++i) {
        const int c = tid + i * 256;
        ar[i] = *(const f32x4*)(xb + (size_t)(c >> 4) * DIN + (kt + 1) * BK + (c & 15) * 4);
      }
      #pragma unroll
      for (int j = 0; j < 4; ++j) {
        const int ch = w * 4 + j;
        const int L = ch * 1024 + lane * 16;
        const int o_l = L >> 7;
        const int kb = (L & 127) ^ ((o_l & 7) << 4);
        gload_lds16(wbase + (size_t)o_l * (DIN * 2) + (size_t)(kt + 1) * (BK * 2) + kb,
                    (char*)(&sB[nxt][0]) + ch * 1024);
      }
    }
    const char* Ab = (const char*)(&sA[cur][0]);
    const char* Bb = (const char*)(&sB[cur][0]);
    #pragma unroll
    for (int ks = 0; ks < 2; ++ks) {
      short8 av[4], bv[4];
      #pragma unroll
      for (int mf = 0; mf < 4; ++mf) {
        const int r = wm * 64 + mf * 16 + (lane & 15);
        av[mf] = *(const short8*)(Ab + r * (LDA * 2) + ks * 64 + ((lane >> 4) << 4));
      }
      #pragma unroll
      for (int nf = 0; nf < 4; ++nf) {
        const int o = wn * 64 + nf * 16 + (lane & 15);
        const int kb = (ks * 64 + ((lane >> 4) << 4)) ^ ((o & 7) << 4);
        bv[nf] = *(const short8*)(Bb + o * 128 + kb);
      }
      #pragma unroll
      for (int mf = 0; mf < 4; ++mf)
        #pragma unroll
        for (int nf = 0; nf < 4; ++nf)
          acc[mf][nf] = __builtin_amdgcn_mfma_f32_16x16x32_bf16(av[mf], bv[nf], acc[mf][nf], 0, 0, 0);
    }
    if (kt + 1 < NKT) {
      #pragma unroll
      for (int i = 0; i < 8; ++i) {
        const int c = tid + i * 256;
        uint2 hv;
        hv.x = f2bf(ar[i].x) | ((unsigned)f2bf(ar[i].y) << 16);
        hv.y = f2bf(ar[i].z) | ((unsigned)f2bf(ar[i].w) << 16);
        *(uint2*)((char*)(&sA[nxt][0]) + (c >> 4) * (LDA * 2) + (c & 15) * 8) = hv;
      }
    }
    __syncthreads();
    cur = nxt;
  }

  #pragma unroll
  for (int nf = 0; nf < 4; ++nf) {
    const int col = col0 + wn * 64 + nf * 16 + (lane & 15);
    const float bv = bias[col * 16 + e];
    #pragma unroll
    for (int mf = 0; mf < 4; ++mf) {
      const int row = row0 + wm * 64 + mf * 16 + ((lane >> 4) << 2);
      const f32x4 v = acc[mf][nf];
      #pragma unroll
      for (int r = 0; r < 4; ++r) {
        const float y = v[r] + bv;
        out[(size_t)(row + r) * DOUT + col] = y * (1.0f / (1.0f + __expf(-y)));
      }
    }
  }
}

extern "C" void kernel_launch(void* const* d_in, const int* in_sizes, int n_in,
                              void* d_out, int out_size, void* d_ws, size_t ws_size,
                              hipStream_t stream) {
  const float* x    = (const float*)d_in[0];
  // d_in[1] = expert_ids_sorted (int32) — equal split is static, unused.
  const float* W    = (const float*)d_in[2];
  const float* bias = (const float*)d_in[3];
  float* out = (float*)d_out;

  const size_t wt_bytes = (size_t)E_ * DOUT * DIN * 2;        // 64 MiB
  const size_t xs_bytes = (size_t)NTOK * DIN * 2;             // 128 MiB

  unsigned short* Wt = (unsigned short*)d_ws;

  if (ws_size >= wt_bytes + xs_bytes) {
    unsigned short* xsw = (unsigned short*)((char*)d_ws + wt_bytes);
    prep_x<<<2048, 256, 0, stream>>>(x, xsw);
    prep_w<true><<<2048, 256, 0, stream>>>(W, Wt);
    static const bool lds_ok =
        (hipFuncSetAttribute(reinterpret_cast<const void*>(moe_gemm8),
                             hipFuncAttributeMaxDynamicSharedMemorySize, 131072) == hipSuccess);
    if (lds_ok) {
      moe_gemm8<<<2048, 512, 131072, stream>>>(xsw, Wt, bias, out);
    } else {
      moe_gemm_s<<<8192, 256, 0, stream>>>(xsw, Wt, bias, out);
    }
  } else {
    prep_w_plain<<<2048, 256, 0, stream>>>(W, Wt);
    moe_gemm_f32a<<<8192, 256, 0, stream>>>(x, Wt, bias, out);
  }
}